// Round 2
// baseline (283.712 us; speedup 1.0000x reference)
//
#include <hip/hip_runtime.h>
#include <hip/hip_bf16.h>
#include <stdint.h>

// Bahdanau attention. B=32, T=2048, D=512, U=512.
// d_out: context[B,D] (16384 f32) then attention_weights[B,T,1] (65536 f32)

#define B_DIM 32
#define T_DIM 2048
#define D_DIM 512
#define U_DIM 512
#define M_DIM (B_DIM * T_DIM)   // 65536 rows

typedef short bf16x8 __attribute__((ext_vector_type(8)));
typedef float f32x4 __attribute__((ext_vector_type(4)));

__device__ __forceinline__ float fast_tanh(float x) {
    float e = __expf(2.0f * x);
    return 1.0f - __fdividef(2.0f, e + 1.0f);
}

// scalar RNE f32->bf16 (prep only)
__device__ __forceinline__ short bf16r(float x) {
    unsigned u = __float_as_uint(x);
    u += 0x7fffu + ((u >> 16) & 1u);
    return (short)(u >> 16);
}

// packed RNE conversion for the score hot loop (f32x4 pair -> 8 bf16)
__device__ __forceinline__ bf16x8 pack8v(f32x4 a, f32x4 b) {
    union { __hip_bfloat162 h[4]; bf16x8 v; } u;
    u.h[0] = __float22bfloat162_rn(make_float2(a[0], a[1]));
    u.h[1] = __float22bfloat162_rn(make_float2(a[2], a[3]));
    u.h[2] = __float22bfloat162_rn(make_float2(b[0], b[1]));
    u.h[3] = __float22bfloat162_rn(make_float2(b[2], b[3]));
    return u.v;
}

// async global->LDS, 16B per lane (dest = wave-uniform base + lane*16;
// call sites keep lane-linear LDS addresses). R3/R4-proven correct.
__device__ __forceinline__ void g2lds16(const void* g, void* lds) {
    auto gp = reinterpret_cast<const __attribute__((address_space(1))) unsigned int*>(
        reinterpret_cast<uintptr_t>(g));
    auto lp = reinterpret_cast<__attribute__((address_space(3))) unsigned int*>(
        (unsigned int)(uintptr_t)lds);
    __builtin_amdgcn_global_load_lds(gp, lp, 16, 0, 0);
}

// ---------------------------------------------------------------------------
// W1T layout in 16-byte units (8 bf16 along k):
//   unit n = ut*16384 + kstep*1024 + kc*256 + uu
//   where u = ut*256+uu, k = kstep*32 + kc*8 + j.
// Chunk (ut,kstep) = 1024 units = 16 KiB, contiguous -> pure linear
// global_load_lds staging; frag reads are 256B-contiguous per quad (kc).
// ---------------------------------------------------------------------------

// Kernel 1: prep. (unchanged)
__global__ void prep_kernel(const float* __restrict__ W1_w,
                            const float* __restrict__ W1_b,
                            const float* __restrict__ W2_w,
                            const float* __restrict__ W2_b,
                            const float* __restrict__ query,
                            unsigned short* __restrict__ W1T,
                            float* __restrict__ qb) {
    __shared__ float red[256];
    const int tid = threadIdx.x;
    if (blockIdx.x < 128) {
        int n = blockIdx.x * 256 + tid;   // unit id 0..32767
        int uu    = n & 255;
        int kc    = (n >> 8) & 3;
        int kstep = (n >> 10) & 15;
        int ut    = n >> 14;
        int u  = ut * 256 + uu;
        int k0 = kstep * 32 + kc * 8;
        bf16x8 pk;
#pragma unroll
        for (int j = 0; j < 8; ++j)
            pk[j] = bf16r(W1_w[(size_t)(k0 + j) * U_DIM + u]);  // coalesced in u
        ((bf16x8*)W1T)[n] = pk;
    } else {
        int bid = blockIdx.x - 128;       // 0..255
        int b  = bid >> 3;
        int ug = bid & 7;
        int u  = ug * 64 + (tid & 63);
        int dq = tid >> 6;                // 0..3 (128 d each)
        const float* q  = query + b * D_DIM + dq * 128;
        const float* w2 = W2_w + (size_t)(dq * 128) * U_DIM + u;
        float acc = 0.f;
#pragma unroll 8
        for (int d = 0; d < 128; ++d)
            acc += q[d] * w2[(size_t)d * U_DIM];
        red[tid] = acc;
        __syncthreads();
        if (tid < 64) {
            qb[b * U_DIM + u] = red[tid] + red[tid + 64] + red[tid + 128]
                              + red[tid + 192] + W2_b[u] + W1_b[u];
        }
    }
}

// ---------------------------------------------------------------------------
// Kernel 2: fused score GEMM. 1024 blocks x 512 thr (8 waves) -- R0's proven
// compute structure (128m x 256u block, acc[2][8]/wave, B-frag reused across
// 2 m-tiles) with a counted-vmcnt pipeline for the sync structure:
//
//  * B-slab staging: global_load_lds (no reg dest -> no reg-copy hazard),
//    TRIPLE-buffered, staged 2 bodies ahead, drained by manual counted
//    s_waitcnt vmcnt(N) one body before its consuming barrier (m201 pattern).
//  * A-operands: PLAIN f32x4 loads prefetched 1 body ahead; the compiler
//    tracks them (and the global_load_lds builtins) and inserts correctly
//    counted waits at first use. No inline-asm register loads (R1's bug).
//  * Raw s_barrier (no vmcnt(0) drain); sched_barrier(0) pins each section.
//
// Per body KS (program order, per thread):
//   B_KS | stage st(KS+2) [2 ops, KS<=13] | A(KS+1) [4 plain loads, KS<=14]
//   | manual wait | pack A(KS) + 8 ds_read_b128 + 16 MFMA.
// Outstanding at manual wait, KS<=13 (oldest first):
//   st(KS+1)x2, A(KS)x4, st(KS+2)x2, A(KS+1)x4 = 12 -> vmcnt(10) drains
//   exactly st(KS+1), before B_{KS+1}. KS=14: 10 outstanding -> vmcnt(8)
//   drains st(15). KS=15: nothing issued, no manual wait.
// Hazards: reads of slab K finish pre-B_{K+1} (MFMA deps force lgkm waits);
//   st(K+2) targets buf[(K-1)%3] whose readers finished before B_K; manual
//   waits can only OVER-wait if the compiler adds VMEM -> safe direction.
// ---------------------------------------------------------------------------
template <int KS>
__device__ __forceinline__ void score_step(
        const unsigned short* __restrict__ wsrc,
        unsigned char* __restrict__ sm0,
        int tid,
        const float* __restrict__ arow0,
        const float* __restrict__ arow1,
        const unsigned char* __restrict__ bb,
        f32x4& c00, f32x4& c01, f32x4& c10, f32x4& c11,   // A(KS)   (consumed)
        f32x4& n00, f32x4& n01, f32x4& n10, f32x4& n11,   // A(KS+1) (produced)
        f32x4 (&acc)[2][8]) {
    __builtin_amdgcn_s_barrier();                 // B_KS: slab KS published
    __builtin_amdgcn_sched_barrier(0);
    if constexpr (KS <= 13) {
        // stage slab KS+2 into the buffer whose readers finished before B_KS
        const unsigned short* src = wsrc + (size_t)(KS + 2) * 8192;
        unsigned char* nbuf = sm0 + ((KS + 2) % 3) * 16384;
        g2lds16(src + (size_t)tid * 8,        nbuf + tid * 16);
        g2lds16(src + 4096 + (size_t)tid * 8, nbuf + 8192 + tid * 16);
    }
    __builtin_amdgcn_sched_barrier(0);
    if constexpr (KS <= 14) {
        n00 = *(const f32x4*)(arow0 + (KS + 1) * 32);
        n01 = *(const f32x4*)(arow0 + (KS + 1) * 32 + 4);
        n10 = *(const f32x4*)(arow1 + (KS + 1) * 32);
        n11 = *(const f32x4*)(arow1 + (KS + 1) * 32 + 4);
    }
    __builtin_amdgcn_sched_barrier(0);
    if constexpr (KS <= 13) {
        asm volatile("s_waitcnt vmcnt(10)" ::: "memory");
    } else if constexpr (KS == 14) {
        asm volatile("s_waitcnt vmcnt(8)" ::: "memory");
    }
    __builtin_amdgcn_sched_barrier(0);

    bf16x8 a0 = pack8v(c00, c01);     // compiler inserts its own (counted) wait
    bf16x8 a1 = pack8v(c10, c11);
    const unsigned char* bbk = bb + (KS % 3) * 16384;
#pragma unroll
    for (int ui = 0; ui < 8; ++ui) {
        bf16x8 bf = *(const bf16x8*)(bbk + ui * 256);   // 256B-contig/quad
        acc[0][ui] = __builtin_amdgcn_mfma_f32_16x16x32_bf16(a0, bf, acc[0][ui], 0, 0, 0);
        acc[1][ui] = __builtin_amdgcn_mfma_f32_16x16x32_bf16(a1, bf, acc[1][ui], 0, 0, 0);
    }
    __builtin_amdgcn_sched_barrier(0);            // keep compute inside this body
}

__global__ __launch_bounds__(512, 4) void score_kernel(
        const float* __restrict__ values,
        const unsigned short* __restrict__ W1T,
        const float* __restrict__ qb,
        const float* __restrict__ Vw,
        float* __restrict__ sP) {
    __shared__ __align__(16) unsigned char smem[3][16384];

    const int tid  = threadIdx.x;
    const int lane = tid & 63;
    const int w    = tid >> 6;       // 0..7
    const int l15  = lane & 15;
    const int quad = lane >> 4;
    const int wr   = w >> 1;         // 0..3 : 32 m-rows each
    const int wc   = w & 1;          // 0..1 : 128 u each
    const int ut   = blockIdx.x & 1;
    const int mb   = (blockIdx.x >> 1) * 128;
    const int b    = mb >> 11;       // 128 | 2048

    const float* arow0 = values + (size_t)(mb + wr * 32 + l15) * D_DIM + quad * 8;
    const float* arow1 = arow0 + 16 * D_DIM;
    const unsigned short* wsrc = W1T + (size_t)ut * 16 * 8192;
    unsigned char* sm0 = &smem[0][0];
    const unsigned char* bb = sm0 + (size_t)(quad * 256 + wc * 128 + l15) * 16;

    // ---- prologue: stage slabs 0,1; issue A(0); drain st(0) before B_0 ----
    g2lds16(wsrc + (size_t)tid * 8,        sm0 + tid * 16);
    g2lds16(wsrc + 4096 + (size_t)tid * 8, sm0 + 8192 + tid * 16);
    __builtin_amdgcn_sched_barrier(0);
    g2lds16(wsrc + 8192 + (size_t)tid * 8,        sm0 + 16384 + tid * 16);
    g2lds16(wsrc + 8192 + 4096 + (size_t)tid * 8, sm0 + 16384 + 8192 + tid * 16);
    __builtin_amdgcn_sched_barrier(0);
    f32x4 cA00 = *(const f32x4*)(arow0);
    f32x4 cA01 = *(const f32x4*)(arow0 + 4);
    f32x4 cA10 = *(const f32x4*)(arow1);
    f32x4 cA11 = *(const f32x4*)(arow1 + 4);
    __builtin_amdgcn_sched_barrier(0);
    // outstanding: st(0)x2, st(1)x2, A(0)x4 = 8 -> drain st(0) pair
    asm volatile("s_waitcnt vmcnt(6)" ::: "memory");
    __builtin_amdgcn_sched_barrier(0);

    f32x4 cB00, cB01, cB10, cB11;
    f32x4 acc[2][8] = {};

    score_step<0 >(wsrc, sm0, tid, arow0, arow1, bb, cA00, cA01, cA10, cA11, cB00, cB01, cB10, cB11, acc);
    score_step<1 >(wsrc, sm0, tid, arow0, arow1, bb, cB00, cB01, cB10, cB11, cA00, cA01, cA10, cA11, acc);
    score_step<2 >(wsrc, sm0, tid, arow0, arow1, bb, cA00, cA01, cA10, cA11, cB00, cB01, cB10, cB11, acc);
    score_step<3 >(wsrc, sm0, tid, arow0, arow1, bb, cB00, cB01, cB10, cB11, cA00, cA01, cA10, cA11, acc);
    score_step<4 >(wsrc, sm0, tid, arow0, arow1, bb, cA00, cA01, cA10, cA11, cB00, cB01, cB10, cB11, acc);
    score_step<5 >(wsrc, sm0, tid, arow0, arow1, bb, cB00, cB01, cB10, cB11, cA00, cA01, cA10, cA11, acc);
    score_step<6 >(wsrc, sm0, tid, arow0, arow1, bb, cA00, cA01, cA10, cA11, cB00, cB01, cB10, cB11, acc);
    score_step<7 >(wsrc, sm0, tid, arow0, arow1, bb, cB00, cB01, cB10, cB11, cA00, cA01, cA10, cA11, acc);
    score_step<8 >(wsrc, sm0, tid, arow0, arow1, bb, cA00, cA01, cA10, cA11, cB00, cB01, cB10, cB11, acc);
    score_step<9 >(wsrc, sm0, tid, arow0, arow1, bb, cB00, cB01, cB10, cB11, cA00, cA01, cA10, cA11, acc);
    score_step<10>(wsrc, sm0, tid, arow0, arow1, bb, cA00, cA01, cA10, cA11, cB00, cB01, cB10, cB11, acc);
    score_step<11>(wsrc, sm0, tid, arow0, arow1, bb, cB00, cB01, cB10, cB11, cA00, cA01, cA10, cA11, acc);
    score_step<12>(wsrc, sm0, tid, arow0, arow1, bb, cA00, cA01, cA10, cA11, cB00, cB01, cB10, cB11, acc);
    score_step<13>(wsrc, sm0, tid, arow0, arow1, bb, cB00, cB01, cB10, cB11, cA00, cA01, cA10, cA11, acc);
    score_step<14>(wsrc, sm0, tid, arow0, arow1, bb, cA00, cA01, cA10, cA11, cB00, cB01, cB10, cB11, acc);
    score_step<15>(wsrc, sm0, tid, arow0, arow1, bb, cB00, cB01, cB10, cB11, cA00, cA01, cA10, cA11, acc);

    // ---- epilogue (once): tanh + Vw, reduce over u ----  (R0, unchanged)
    const int ub = ut * 256 + wc * 128 + l15;
    float sm[2][4] = {};
#pragma unroll
    for (int ui = 0; ui < 8; ++ui) {
        const int u = ub + ui * 16;
        const float qv = qb[b * U_DIM + u];
        const float vw = Vw[u];
#pragma unroll
        for (int mt = 0; mt < 2; ++mt)
#pragma unroll
            for (int r = 0; r < 4; ++r)
                sm[mt][r] += fast_tanh(acc[mt][ui][r] + qv) * vw;
    }
#pragma unroll
    for (int mt = 0; mt < 2; ++mt)
#pragma unroll
        for (int r = 0; r < 4; ++r) {
            float v = sm[mt][r];
            v += __shfl_xor(v, 1, 64);
            v += __shfl_xor(v, 2, 64);
            v += __shfl_xor(v, 4, 64);
            v += __shfl_xor(v, 8, 64);
            sm[mt][r] = v;
        }
    if (l15 == 0) {
        const int slice = ut * 2 + wc;
#pragma unroll
        for (int mt = 0; mt < 2; ++mt)
#pragma unroll
            for (int r = 0; r < 4; ++r)
                sP[(size_t)slice * M_DIM + mb + wr * 32 + mt * 16 + quad * 4 + r] = sm[mt][r];
    }
}

// ---------------------------------------------------------------------------
// Kernel 3: softmax over T per batch; sums the 4 score slices; writes weights.
// ---------------------------------------------------------------------------
__global__ void softmax_kernel(const float* __restrict__ sP,
                               float* __restrict__ out) {
    const int b = blockIdx.x;
    const int tid = threadIdx.x;

    float v[8];
    float mx = -1e30f;
#pragma unroll
    for (int i = 0; i < 8; ++i) {
        int m = b * T_DIM + i * 256 + tid;
        v[i] = sP[m] + sP[M_DIM + m] + sP[2 * M_DIM + m] + sP[3 * M_DIM + m];
        mx = fmaxf(mx, v[i]);
    }
#pragma unroll
    for (int off = 1; off < 64; off <<= 1)
        mx = fmaxf(mx, __shfl_xor(mx, off, 64));
    __shared__ float redm[4];
    if ((tid & 63) == 0) redm[tid >> 6] = mx;
    __syncthreads();
    mx = fmaxf(fmaxf(redm[0], redm[1]), fmaxf(redm[2], redm[3]));

    float sum = 0.f;
#pragma unroll
    for (int i = 0; i < 8; ++i) {
        v[i] = __expf(v[i] - mx);
        sum += v[i];
    }
#pragma unroll
    for (int off = 1; off < 64; off <<= 1)
        sum += __shfl_xor(sum, off, 64);
    __shared__ float reds[4];
    if ((tid & 63) == 0) reds[tid >> 6] = sum;
    __syncthreads();
    sum = reds[0] + reds[1] + reds[2] + reds[3];

    const float inv = 1.0f / sum;
#pragma unroll
    for (int i = 0; i < 8; ++i)
        out[B_DIM * D_DIM + b * T_DIM + i * 256 + tid] = v[i] * inv;
}

// ---------------------------------------------------------------------------
// Kernel 4: context partials. grid (32 tc, 32 b) x 256 thr. Block = 64 t x
// 512 d; two t-interleaved halves combined in LDS; partial -> P (no atomics).
// ---------------------------------------------------------------------------
__global__ void context_kernel(const float* __restrict__ values,
                               const float* __restrict__ weights,
                               float* __restrict__ P) {
    __shared__ float sw[64];
    __shared__ float red[512];
    const int tc = blockIdx.x;   // 0..31 (64 t each)
    const int b  = blockIdx.y;
    const int tid = threadIdx.x;
    const int d4 = tid & 127;    // float4 column
    const int th = tid >> 7;     // t-interleave half

    if (tid < 64) sw[tid] = weights[b * T_DIM + tc * 64 + tid];
    __syncthreads();

    const float4* vb = (const float4*)(values + ((size_t)b * T_DIM + tc * 64) * D_DIM) + d4;
    float4 acc = {0.f, 0.f, 0.f, 0.f};
#pragma unroll 8
    for (int i = th; i < 64; i += 2) {
        float wv = sw[i];
        float4 vv = vb[(size_t)i * 128];
        acc.x += wv * vv.x; acc.y += wv * vv.y;
        acc.z += wv * vv.z; acc.w += wv * vv.w;
    }
    if (th == 1) ((float4*)red)[d4] = acc;
    __syncthreads();
    if (th == 0) {
        float4 o = ((float4*)red)[d4];
        acc.x += o.x; acc.y += o.y; acc.z += o.z; acc.w += o.w;
        *(float4*)(P + ((size_t)(b * 32 + tc)) * 512 + d4 * 4) = acc;
    }
}

// Kernel 5: reduce the 32 t-chunk partials -> context output.
__global__ void reduce_kernel(const float* __restrict__ P,
                              float* __restrict__ ctx) {
    const int g = blockIdx.x * 256 + threadIdx.x;   // 0..16383
    const int b = g >> 9, d = g & 511;
    float s = 0.f;
#pragma unroll
    for (int tc = 0; tc < 32; ++tc)
        s += P[((size_t)(b * 32 + tc)) * 512 + d];
    ctx[g] = s;
}

// ---------------------------------------------------------------------------
extern "C" void kernel_launch(void* const* d_in, const int* in_sizes, int n_in,
                              void* d_out, int out_size, void* d_ws, size_t ws_size,
                              hipStream_t stream) {
    const float* values = (const float*)d_in[0];
    const float* query  = (const float*)d_in[1];
    const float* W1_w   = (const float*)d_in[2];
    const float* W1_b   = (const float*)d_in[3];
    const float* W2_w   = (const float*)d_in[4];
    const float* W2_b   = (const float*)d_in[5];
    const float* V_w    = (const float*)d_in[6];
    // V_b (d_in[7]) dropped: softmax is shift-invariant.

    float* out = (float*)d_out;

    unsigned char* ws = (unsigned char*)d_ws;
    unsigned short* W1T = (unsigned short*)(ws);             // 512 KiB
    float* qb = (float*)(ws + 524288);                       // 64 KiB
    float* sP = (float*)(ws + 524288 + 65536);               // 1 MiB (4 slices)
    float* P  = (float*)(ws + 524288 + 65536 + 1048576);     // 2 MiB

    prep_kernel<<<384, 256, 0, stream>>>(W1_w, W1_b, W2_w, W2_b, query, W1T, qb);
    score_kernel<<<1024, 512, 0, stream>>>(values, W1T, qb, V_w, sP);
    softmax_kernel<<<B_DIM, 256, 0, stream>>>(sP, out);
    context_kernel<<<dim3(32, B_DIM), 256, 0, stream>>>(values, out + B_DIM * D_DIM, P);
    reduce_kernel<<<64, 256, 0, stream>>>(P, out);
}